// Round 4
// baseline (318.301 us; speedup 1.0000x reference)
//
#include <hip/hip_runtime.h>
#include <stdint.h>

#define NB 64    // scan steps (B)
#define NT 128   // T
#define NF 1024  // F
#define NS 512   // S
#define NM 2048  // M
#define SQRT_S 22.627417f  // correctly-rounded f32 of sqrt(512)

// 0.5 - hard_sigmoid(x - s), numpy-identical per-op rounding.
__device__ __forceinline__ float comp_of(float x, float s) {
    float d = __fsub_rn(x, s);
    float t = __fadd_rn(__fmul_rn(0.2f, d), 0.5f);
    t = fminf(fmaxf(t, 0.0f), 1.0f);
    return __fsub_rn(0.5f, t);
}

// order-isomorphic f32 <-> u32 (NaN-free). Invertible: decode gives bit-exact float.
__device__ __forceinline__ unsigned fkey(float x) {
    unsigned u = __float_as_uint(x);
    return (u & 0x80000000u) ? ~u : (u | 0x80000000u);
}
__device__ __forceinline__ float fkeyInv(unsigned k) {
    return (k & 0x80000000u) ? __uint_as_float(k & 0x7fffffffu) : __uint_as_float(~k);
}
// larger key = larger value, ties -> smaller slot (np.argmax first-index semantics).
__device__ __forceinline__ unsigned long long packKey(float v, int m) {
    return ((unsigned long long)fkey(v) << 32) | (unsigned)(NM - m);
}

// Row code -> pointer. code<NM: original memory row; <2NM: q-blend row (vecq[b]);
// <3NM: UMS row b; else: states row b (last timestep).
__device__ __forceinline__ const float* rowPtr(int code, const float* memory,
                                               const float* vecq, const float* UMS,
                                               const float* states) {
    if (code < NM)     return memory + (size_t)code * NF;
    if (code < 2 * NM) return vecq + (size_t)(code - NM) * NF;
    if (code < 3 * NM) return UMS + (size_t)(code - 2 * NM) * NF;
    return states + ((size_t)(code - 3 * NM) * NT + NT - 1) * NF;
}

// ---- cheap cross-lane helpers (VALU/SALU pipes, no ds ops) ----
__device__ __forceinline__ unsigned rflu(unsigned v) {
    return (unsigned)__builtin_amdgcn_readfirstlane((int)v);
}
__device__ __forceinline__ int rdl(int v, int l) { return __builtin_amdgcn_readlane(v, l); }
__device__ __forceinline__ float rdlf(float v, int l) {
    return __uint_as_float((unsigned)__builtin_amdgcn_readlane((int)__float_as_uint(v), l));
}
// 16-lane (row) max via DPP. Result is ROW-UNIFORM: every lane of each 16-lane row
// holds its row's max (no readfirstlane needed for row-local consumers).
__device__ __forceinline__ unsigned row16MaxU32(unsigned x) {
    unsigned t;
    t = (unsigned)__builtin_amdgcn_update_dpp(0, (int)x, 0xB1, 0xF, 0xF, true);   // quad_perm(1,0,3,2)
    x = (t > x) ? t : x;
    t = (unsigned)__builtin_amdgcn_update_dpp(0, (int)x, 0x4E, 0xF, 0xF, true);   // quad_perm(2,3,0,1)
    x = (t > x) ? t : x;
    t = (unsigned)__builtin_amdgcn_update_dpp(0, (int)x, 0x141, 0xF, 0xF, true);  // row_half_mirror
    x = (t > x) ? t : x;
    t = (unsigned)__builtin_amdgcn_update_dpp(0, (int)x, 0x140, 0xF, 0xF, true);  // row_mirror
    x = (t > x) ? t : x;
    return x;
}

// ---- 64-wide butterflies (LDS-mode only; a few early steps) ----
__device__ __forceinline__ unsigned waveMaxU32(unsigned k) {
    #pragma unroll
    for (int off = 1; off < 64; off <<= 1) {
        unsigned o = __shfl_xor(k, off, 64);
        if (o > k) k = o;
    }
    return k;
}

// ---- fused: routes stage-1 (first 1024 blocks) + predorig/memLast (next 2048) ----
__global__ void __launch_bounds__(256) k_pre(
        const float* __restrict__ mr, const float* __restrict__ memory,
        const float* __restrict__ states,
        float* __restrict__ pMin, float* __restrict__ pMax,
        unsigned long long* __restrict__ predOrig, float* __restrict__ memLast,
        int doRoutes)
{
    int bid = blockIdx.x;
    if (bid < NB * 16) {
        if (!doRoutes) return;
        int b = bid >> 4, fb = (bid >> 2) & 3, seg = bid & 3;
        int f = fb * 256 + threadIdx.x;
        const float* base = mr + (size_t)b * NS * NF + (size_t)seg * (NS / 4) * NF + f;
        float mn0 = base[0],      mx0 = mn0;
        float mn1 = base[NF],     mx1 = mn1;
        float mn2 = base[2 * NF], mx2 = mn2;
        float mn3 = base[3 * NF], mx3 = mn3;
        #pragma unroll 4
        for (int s = 4; s < NS / 4; s += 4) {
            float v0 = base[(size_t)s * NF];
            float v1 = base[(size_t)(s + 1) * NF];
            float v2 = base[(size_t)(s + 2) * NF];
            float v3 = base[(size_t)(s + 3) * NF];
            mn0 = fminf(mn0, v0); mx0 = fmaxf(mx0, v0);
            mn1 = fminf(mn1, v1); mx1 = fmaxf(mx1, v1);
            mn2 = fminf(mn2, v2); mx2 = fmaxf(mx2, v2);
            mn3 = fminf(mn3, v3); mx3 = fmaxf(mx3, v3);
        }
        size_t o = ((size_t)seg * NB + b) * NF + f;
        pMin[o] = fminf(fminf(mn0, mn1), fminf(mn2, mn3));
        pMax[o] = fmaxf(fmaxf(mx0, mx1), fmaxf(mx2, mx3));
        return;
    }
    // predorig part
    int m = bid - NB * 16, t = threadIdx.x;
    const float4* rowp = (const float4*)(memory + (size_t)m * NF);
    float4 v = rowp[t];
    unsigned long long mask = 0ull;
    for (int b = 0; b < NB; ++b) {
        const float4* spp = (const float4*)(states + ((size_t)b * NT + NT - 1) * NF);
        float4 s = spp[t];
        bool p = (comp_of(v.x, s.x) >= 0.45f) | (comp_of(v.y, s.y) >= 0.45f)
               | (comp_of(v.z, s.z) >= 0.45f) | (comp_of(v.w, s.w) >= 0.45f);
        if (p) mask |= (1ull << b);
    }
    __shared__ unsigned long long sm[256];
    sm[t] = mask;
    __syncthreads();
    for (int off = 128; off > 0; off >>= 1) {
        if (t < off) sm[t] |= sm[t + off];
        __syncthreads();
    }
    if (t == 0)   predOrig[m] = sm[0];
    if (t == 255) memLast[m] = v.w;
}

// Shared epilogue: UMS row, condS (written once per b), updIdxS.
__device__ __forceinline__ void routes_epilogue(int b, int f, float mn, float mx,
        const float* mr, const float* states, float* UMS, float* updIdxS, int* condS,
        int* anyf) {
    float sv = states[((size_t)b * NT + NT - 1) * NF + f];
    float compHi = comp_of(mn, sv);
    float compLo = comp_of(mx, sv);
    float maxabs = fmaxf(compHi, -compLo);
    float cs   = __fmul_rn(SQRT_S, maxabs);
    float omcs = __fsub_rn(1.0f, cs);
    UMS[(size_t)b * NF + f] = __fadd_rn(__fmul_rn(mx, cs), __fmul_rn(sv, omcs));
    if (f == 0) *anyf = 0;
    __syncthreads();
    if (compHi >= 0.45f) atomicOr(anyf, 1);
    __syncthreads();
    if (f == 0) condS[b] = (*anyf) ? 1 : 0;
    if (f == NF - 1) {
        float mr0l = mr[(size_t)b * NS * NF + NF - 1];  // mr[b, 0, F-1]
        updIdxS[b] = __fadd_rn(__fmul_rn(mr0l, cs), __fmul_rn(sv, omcs));
    }
}

// ---- stage 2: combine segments + epilogue. One 1024-thread block per b. ----
__global__ void __launch_bounds__(1024) k_routes2(
        const float* __restrict__ pMin, const float* __restrict__ pMax,
        const float* __restrict__ mr, const float* __restrict__ states,
        float* __restrict__ UMS, float* __restrict__ updIdxS,
        int* __restrict__ condS) {
    __shared__ int anyf;
    int b = blockIdx.x;
    int f = threadIdx.x;
    float mn = INFINITY, mx = -INFINITY;
    #pragma unroll
    for (int seg = 0; seg < 4; ++seg) {
        size_t o = ((size_t)seg * NB + b) * NF + f;
        mn = fminf(mn, pMin[o]);
        mx = fmaxf(mx, pMax[o]);
    }
    routes_epilogue(b, f, mn, mx, mr, states, UMS, updIdxS, condS, &anyf);
}

// ---- fallback single-stage (if ws too small). One 1024-thread block per b. ----
__global__ void __launch_bounds__(1024) k_routes(
        const float* __restrict__ mr, const float* __restrict__ states,
        float* __restrict__ UMS, float* __restrict__ updIdxS,
        int* __restrict__ condS) {
    __shared__ int anyf;
    int b = blockIdx.x;
    int f = threadIdx.x;
    const float* base = mr + (size_t)b * NS * NF + f;
    float mn0 = base[0],      mx0 = mn0;
    float mn1 = base[NF],     mx1 = mn1;
    float mn2 = base[2 * NF], mx2 = mn2;
    float mn3 = base[3 * NF], mx3 = mn3;
    #pragma unroll 4
    for (int s = 4; s < NS; s += 4) {
        float v0 = base[(size_t)s * NF];
        float v1 = base[(size_t)(s + 1) * NF];
        float v2 = base[(size_t)(s + 2) * NF];
        float v3 = base[(size_t)(s + 3) * NF];
        mn0 = fminf(mn0, v0); mx0 = fmaxf(mx0, v0);
        mn1 = fminf(mn1, v1); mx1 = fmaxf(mx1, v1);
        mn2 = fminf(mn2, v2); mx2 = fmaxf(mx2, v2);
        mn3 = fminf(mn3, v3); mx3 = fmaxf(mx3, v3);
    }
    float mn = fminf(fminf(mn0, mn1), fminf(mn2, mn3));
    float mx = fmaxf(fmaxf(mx0, mx1), fmaxf(mx2, mx3));
    routes_epilogue(b, f, mn, mx, mr, states, UMS, updIdxS, condS, &anyf);
}

// Sequential scan, SINGLE WAVE, group-collapsed carry.
// Steady state: groups confined to lanes 0..15, reductions via row-uniform DPP
// (no readfirstlane on control path), tie-breaks skipped when the max is unique,
// and the q-blend source-row load issued EARLY / consumed LAST so phases 4-6
// cover its latency. LDS mode covers G>16 (early steps only).
__global__ void __launch_bounds__(64) k_scan(
    const float* __restrict__ states, const float* __restrict__ memory,
    const float* __restrict__ indexIn, const float* __restrict__ UMS,
    const float* __restrict__ updIdxS, const int* __restrict__ condS,
    const unsigned long long* __restrict__ predOrig,
    const float* __restrict__ memLast, float* __restrict__ vecq,
    int* __restrict__ leadCode, float* __restrict__ out)
{
    __shared__ float gLastS[NM];
    __shared__ float gIdxS[NM];
    __shared__ unsigned short gRowS[NM];
    __shared__ unsigned short gMinS[NM];
    __shared__ unsigned long long pOr[NM];
    __shared__ float stLast[NM];
    __shared__ float stIdx[NM];
    __shared__ unsigned short stRow[NM];
    __shared__ unsigned short stMin[NM];
    __shared__ int cntSh;
    __shared__ int mMinSh;

    const int lane = threadIdx.x;

    for (int m = lane; m < NM; m += 64) {
        gRowS[m] = (unsigned short)m;
        gMinS[m] = (unsigned short)m;
        gIdxS[m] = indexIn[m];
        gLastS[m] = memLast[m];
        pOr[m] = predOrig[m];
    }
    // per-step scalars: lane b holds step b's values; broadcast via readlane
    float sF_r = states[((size_t)lane * NT + NT - 1) * NF + NF - 1];
    int   cS_r = condS[lane];
    float uI_r = updIdxS[lane];
    float uL_r = UMS[(size_t)lane * NF + NF - 1];
    __syncthreads();

    int G = NM;
    bool dppMode = false;
    int rowR = 0; unsigned minR = 0;
    float idxR = 0.f, lastR = 0.f;
    unsigned long long predR = 0ull;
    bool valid = false;
    int qCode = -1;                       // last-created q-row cached in registers
    float4 qc0, qc1, qc2, qc3;

    // software prefetch of states rows: load row for step b at step b-1
    const float* sp0 = states + (size_t)(NT - 1) * NF + 16 * lane;
    float4 sN0 = *(const float4*)(sp0 + 0);
    float4 sN1 = *(const float4*)(sp0 + 4);
    float4 sN2 = *(const float4*)(sp0 + 8);
    float4 sN3 = *(const float4*)(sp0 + 12);

    #pragma unroll 1
    for (int b = 0; b < NB; ++b) {
        float4 s0v = sN0, s1v = sN1, s2v = sN2, s3v = sN3;
        if (b + 1 < NB) {
            const float* np = states + ((size_t)(b + 1) * NT + NT - 1) * NF + 16 * lane;
            sN0 = *(const float4*)(np + 0);
            sN1 = *(const float4*)(np + 4);
            sN2 = *(const float4*)(np + 8);
            sN3 = *(const float4*)(np + 12);
        }
        float sF    = rdlf(sF_r, b);   // == s[F-1] == r
        bool condSb = (rdl(cS_r, b) != 0);
        float uIdx  = rdlf(uI_r, b);
        float uLast = rdlf(uL_r, b);

        if (dppMode) {
            // ================= DPP mode (valid lanes subset of 0..15) =================
            // phase 1: argmax comp(last); kept-mask == isMax (fkey bijective);
            // all reduction results row-uniform -> no readfirstlane on control path.
            float c1 = comp_of(lastR, sF);
            unsigned kf = valid ? fkey(c1) : 0u;
            unsigned bkf = row16MaxU32(kf);           // row-uniform over lanes 0..15
            float cqV = fkeyInv(bkf);                 // lane-local, uniform 0..15
            bool isMaxK = valid && (kf == bkf);       // winner candidates (bit-exact)
            bool kept   = valid && (c1 == cqV);       // float ==, reference mask_q
            unsigned long long keepM = __ballot(kept ? 1 : 0);
            int winLane;
            {
                unsigned long long mk = __ballot(isMaxK ? 1 : 0);
                if (__popcll(mk) == 1) winLane = __ffsll(mk) - 1;
                else {
                    unsigned tb = isMaxK ? (unsigned)(NM - (int)minR) : 0u;
                    unsigned btb = row16MaxU32(tb);
                    winLane = __ffsll(__ballot((isMaxK && tb == btb) ? 1 : 0)) - 1;
                }
            }
            bool condQ = (__any((valid && rowR < NM && ((predR >> b) & 1ull)) ? 1 : 0) != 0);
            int srow = rdl(rowR, winLane);

            // phase 2: pool-row full check only if orig bits missed (rare)
            if (!condQ) {
                unsigned long long pm = __ballot((valid && rowR >= NM) ? 1 : 0);
                while (pm) {
                    int gl = __ffsll(pm) - 1; pm &= pm - 1;
                    int prow = rdl(rowR, gl);
                    float4 v0, v1, v2, v3;
                    if (prow == qCode) { v0 = qc0; v1 = qc1; v2 = qc2; v3 = qc3; }
                    else {
                        const float* p = rowPtr(prow, memory, vecq, UMS, states) + 16 * lane;
                        v0 = *(const float4*)(p + 0);
                        v1 = *(const float4*)(p + 4);
                        v2 = *(const float4*)(p + 8);
                        v3 = *(const float4*)(p + 12);
                    }
                    int pr = (comp_of(v0.x, s0v.x) >= 0.45f) | (comp_of(v0.y, s0v.y) >= 0.45f) |
                             (comp_of(v0.z, s0v.z) >= 0.45f) | (comp_of(v0.w, s0v.w) >= 0.45f) |
                             (comp_of(v1.x, s1v.x) >= 0.45f) | (comp_of(v1.y, s1v.y) >= 0.45f) |
                             (comp_of(v1.z, s1v.z) >= 0.45f) | (comp_of(v1.w, s1v.w) >= 0.45f) |
                             (comp_of(v2.x, s2v.x) >= 0.45f) | (comp_of(v2.y, s2v.y) >= 0.45f) |
                             (comp_of(v2.z, s2v.z) >= 0.45f) | (comp_of(v2.w, s2v.w) >= 0.45f) |
                             (comp_of(v3.x, s3v.x) >= 0.45f) | (comp_of(v3.y, s3v.y) >= 0.45f) |
                             (comp_of(v3.z, s3v.z) >= 0.45f) | (comp_of(v3.w, s3v.w) >= 0.45f);
                    if (__any(pr)) { condQ = true; break; }
                }
            }

            // phase 3a: ISSUE source-row loads early (consumed in deferred blend)
            float4 v0, v1, v2, v3;
            unsigned long long mergeM = 0ull;
            if (condQ) {
                if (srow == qCode) { v0 = qc0; v1 = qc1; v2 = qc2; v3 = qc3; }
                else {
                    const float* srcp = rowPtr(srow, memory, vecq, UMS, states) + 16 * lane;
                    v0 = *(const float4*)(srcp + 0);
                    v1 = *(const float4*)(srcp + 4);
                    v2 = *(const float4*)(srcp + 8);
                    v3 = *(const float4*)(srcp + 12);
                }
                // phase 3b: merge bookkeeping (no loads on this path)
                mergeM = __ballot((valid && !kept) ? 1 : 0);
                if (mergeM) {
                    float idxmi  = rdlf(idxR, winLane);
                    float lastmi = rdlf(lastR, winLane);
                    float omc = __fsub_rn(1.0f, cqV);
                    float updIdxQ = __fadd_rn(__fmul_rn(idxmi, omc), __fmul_rn(sF, cqV));
                    float newLast = __fadd_rn(__fmul_rn(lastmi, omc), __fmul_rn(sF, cqV));
                    unsigned mt = (valid && !kept) ? (unsigned)(NM - (int)minR) : 0u;
                    unsigned newMin = (unsigned)NM - row16MaxU32(mt);  // row-uniform
                    int freeLane = __ffsll(~keepM) - 1;   // lowest non-kept lane (<16)
                    if (lane == freeLane) {
                        rowR = NM + b; idxR = updIdxQ; lastR = newLast;
                        minR = newMin; predR = 0ull;
                    }
                    valid = kept || (lane == freeLane);
                }
            }

            // phase 4/5: s-update or empty-update (mutually exclusive)
            if (condSb || !condQ) {
                unsigned kf2 = valid ? fkey(-idxR) : 0u;
                unsigned bkf2 = row16MaxU32(kf2);         // row-uniform
                float mxneg = fkeyInv(bkf2);              // bit-exact max(-idx)
                bool match = valid && (idxR == mxneg);    // float ==, reference mask
                unsigned long long matchM = __ballot(match ? 1 : 0);
                if (matchM) {
                    unsigned newMin;
                    if (__popcll(matchM) == 1) {
                        newMin = (unsigned)rdl((int)minR, __ffsll(matchM) - 1);
                    } else {
                        unsigned mt = match ? (unsigned)(NM - (int)minR) : 0u;
                        newMin = (unsigned)NM - row16MaxU32(mt);
                    }
                    unsigned long long nv = __ballot((valid && !match) ? 1 : 0);
                    int freeLane = __ffsll(~nv) - 1;
                    if (lane == freeLane) {
                        rowR = condSb ? (2 * NM + b) : (3 * NM + b);
                        idxR = condSb ? uIdx : sF;
                        lastR = condSb ? uLast : sF;
                        minR = newMin; predR = 0ull;
                    }
                    valid = (valid && !match) || (lane == freeLane);
                }
            }

            // phase 6: leader = first-argmax(idx); record row code + importance
            unsigned kf3 = valid ? fkey(idxR) : 0u;
            unsigned bkf3 = row16MaxU32(kf3);             // row-uniform
            bool is3 = valid && (kf3 == bkf3);
            unsigned long long m3 = __ballot(is3 ? 1 : 0);
            int lg;
            if (__popcll(m3) == 1) lg = __ffsll(m3) - 1;
            else {
                unsigned tb3 = is3 ? (unsigned)(NM - (int)minR) : 0u;
                unsigned btb3 = row16MaxU32(tb3);
                lg = __ffsll(__ballot((is3 && tb3 == btb3) ? 1 : 0)) - 1;
            }
            int lrow = rdl(rowR, lg);
            if (lane == 0) {
                leadCode[b] = lrow;
                out[(size_t)NB * NF + b] = fkeyInv(bkf3);
            }

            // phase 3c (deferred): blend + store + cache — load latency covered by 4-6
            if (mergeM) {
                float cqA = fkeyInv(rflu(bkf));           // all-lane broadcast
                float omcA = __fsub_rn(1.0f, cqA);
                float* dst = vecq + (size_t)b * NF + 16 * lane;
                float4 o0, o1, o2, o3;
                o0.x = __fadd_rn(__fmul_rn(v0.x, omcA), __fmul_rn(s0v.x, cqA));
                o0.y = __fadd_rn(__fmul_rn(v0.y, omcA), __fmul_rn(s0v.y, cqA));
                o0.z = __fadd_rn(__fmul_rn(v0.z, omcA), __fmul_rn(s0v.z, cqA));
                o0.w = __fadd_rn(__fmul_rn(v0.w, omcA), __fmul_rn(s0v.w, cqA));
                o1.x = __fadd_rn(__fmul_rn(v1.x, omcA), __fmul_rn(s1v.x, cqA));
                o1.y = __fadd_rn(__fmul_rn(v1.y, omcA), __fmul_rn(s1v.y, cqA));
                o1.z = __fadd_rn(__fmul_rn(v1.z, omcA), __fmul_rn(s1v.z, cqA));
                o1.w = __fadd_rn(__fmul_rn(v1.w, omcA), __fmul_rn(s1v.w, cqA));
                o2.x = __fadd_rn(__fmul_rn(v2.x, omcA), __fmul_rn(s2v.x, cqA));
                o2.y = __fadd_rn(__fmul_rn(v2.y, omcA), __fmul_rn(s2v.y, cqA));
                o2.z = __fadd_rn(__fmul_rn(v2.z, omcA), __fmul_rn(s2v.z, cqA));
                o2.w = __fadd_rn(__fmul_rn(v2.w, omcA), __fmul_rn(s2v.w, cqA));
                o3.x = __fadd_rn(__fmul_rn(v3.x, omcA), __fmul_rn(s3v.x, cqA));
                o3.y = __fadd_rn(__fmul_rn(v3.y, omcA), __fmul_rn(s3v.y, cqA));
                o3.z = __fadd_rn(__fmul_rn(v3.z, omcA), __fmul_rn(s3v.z, cqA));
                o3.w = __fadd_rn(__fmul_rn(v3.w, omcA), __fmul_rn(s3v.w, cqA));
                *(float4*)(dst + 0)  = o0;
                *(float4*)(dst + 4)  = o1;
                *(float4*)(dst + 8)  = o2;
                *(float4*)(dst + 12) = o3;
                qc0 = o0; qc1 = o1; qc2 = o2; qc3 = o3; qCode = NM + b;
            }
        } else {
            // ================= LDS mode (G > 16; early steps) =================
            // phase 1
            unsigned long long lk = 0; int lp = 0; bool lo = false;
            for (int g = lane; g < G; g += 64) {
                float c = comp_of(gLastS[g], sF);
                unsigned long long kk = packKey(c, (int)gMinS[g]);
                if (kk > lk) { lk = kk; lp = g; }
                int row = gRowS[g];
                if (row < NM && ((pOr[row] >> b) & 1ull)) lo = true;
            }
            #pragma unroll
            for (int off = 1; off < 64; off <<= 1) {
                unsigned long long ko = (unsigned long long)__shfl_xor((long long)lk, off, 64);
                int po = __shfl_xor(lp, off, 64);
                if (ko > lk) { lk = ko; lp = po; }
            }
            unsigned long long bk = lk; int miG = lp;
            bool condQ = (__any(lo ? 1 : 0) != 0);
            if (!condQ) {
                for (int g = 0; g < G && !condQ; ++g) {
                    int row = gRowS[g];
                    if (row >= NM) {
                        float4 v0, v1, v2, v3;
                        if (row == qCode) { v0 = qc0; v1 = qc1; v2 = qc2; v3 = qc3; }
                        else {
                            const float* p = rowPtr(row, memory, vecq, UMS, states) + 16 * lane;
                            v0 = *(const float4*)(p + 0);
                            v1 = *(const float4*)(p + 4);
                            v2 = *(const float4*)(p + 8);
                            v3 = *(const float4*)(p + 12);
                        }
                        int pr = (comp_of(v0.x, s0v.x) >= 0.45f) | (comp_of(v0.y, s0v.y) >= 0.45f) |
                                 (comp_of(v0.z, s0v.z) >= 0.45f) | (comp_of(v0.w, s0v.w) >= 0.45f) |
                                 (comp_of(v1.x, s1v.x) >= 0.45f) | (comp_of(v1.y, s1v.y) >= 0.45f) |
                                 (comp_of(v1.z, s1v.z) >= 0.45f) | (comp_of(v1.w, s1v.w) >= 0.45f) |
                                 (comp_of(v2.x, s2v.x) >= 0.45f) | (comp_of(v2.y, s2v.y) >= 0.45f) |
                                 (comp_of(v2.z, s2v.z) >= 0.45f) | (comp_of(v2.w, s2v.w) >= 0.45f) |
                                 (comp_of(v3.x, s3v.x) >= 0.45f) | (comp_of(v3.y, s3v.y) >= 0.45f) |
                                 (comp_of(v3.z, s3v.z) >= 0.45f) | (comp_of(v3.w, s3v.w) >= 0.45f);
                        if (__any(pr)) condQ = true;
                    }
                }
            }

            // phase 3: q-update via LDS-staged compaction
            if (condQ) {
                float cq = fkeyInv((unsigned)(bk >> 32));
                float omc = __fsub_rn(1.0f, cq);
                int srow = gRowS[miG];
                float idxmi = gIdxS[miG];
                float lastmi = gLastS[miG];
                float updIdxQ = __fadd_rn(__fmul_rn(idxmi, omc), __fmul_rn(sF, cq));
                float newLast = __fadd_rn(__fmul_rn(lastmi, omc), __fmul_rn(sF, cq));
                float4 v0, v1, v2, v3;
                if (srow == qCode) { v0 = qc0; v1 = qc1; v2 = qc2; v3 = qc3; }
                else {
                    const float* srcp = rowPtr(srow, memory, vecq, UMS, states) + 16 * lane;
                    v0 = *(const float4*)(srcp + 0);
                    v1 = *(const float4*)(srcp + 4);
                    v2 = *(const float4*)(srcp + 8);
                    v3 = *(const float4*)(srcp + 12);
                }

                bool lmerged = false;
                for (int g = lane; g < G; g += 64)
                    if (comp_of(gLastS[g], sF) != cq) lmerged = true;
                if (__any(lmerged ? 1 : 0)) {
                    if (lane == 0) { cntSh = 0; mMinSh = 0x7fffffff; }
                    __syncthreads();
                    int lm = 0x7fffffff;
                    for (int g = lane; g < G; g += 64) {
                        float c = comp_of(gLastS[g], sF);
                        if (c == cq) {
                            int pos = atomicAdd(&cntSh, 1);
                            stRow[pos] = gRowS[g]; stMin[pos] = gMinS[g];
                            stIdx[pos] = gIdxS[g]; stLast[pos] = gLastS[g];
                        } else {
                            int ms = gMinS[g];
                            if (ms < lm) lm = ms;
                        }
                    }
                    if (lm != 0x7fffffff) atomicMin(&mMinSh, lm);
                    __syncthreads();
                    int cnt = cntSh;
                    for (int i = lane; i < cnt; i += 64) {
                        gRowS[i] = stRow[i];
                        gMinS[i] = stMin[i];
                        gIdxS[i] = stIdx[i];
                        gLastS[i] = stLast[i];
                    }
                    if (lane == 0) {
                        gRowS[cnt] = (unsigned short)(NM + b);
                        gIdxS[cnt] = updIdxQ;
                        gLastS[cnt] = newLast;
                        gMinS[cnt] = (unsigned short)mMinSh;
                    }
                    G = cnt + 1;
                    __syncthreads();
                }

                float* dst = vecq + (size_t)b * NF + 16 * lane;
                float4 o0, o1, o2, o3;
                o0.x = __fadd_rn(__fmul_rn(v0.x, omc), __fmul_rn(s0v.x, cq));
                o0.y = __fadd_rn(__fmul_rn(v0.y, omc), __fmul_rn(s0v.y, cq));
                o0.z = __fadd_rn(__fmul_rn(v0.z, omc), __fmul_rn(s0v.z, cq));
                o0.w = __fadd_rn(__fmul_rn(v0.w, omc), __fmul_rn(s0v.w, cq));
                o1.x = __fadd_rn(__fmul_rn(v1.x, omc), __fmul_rn(s1v.x, cq));
                o1.y = __fadd_rn(__fmul_rn(v1.y, omc), __fmul_rn(s1v.y, cq));
                o1.z = __fadd_rn(__fmul_rn(v1.z, omc), __fmul_rn(s1v.z, cq));
                o1.w = __fadd_rn(__fmul_rn(v1.w, omc), __fmul_rn(s1v.w, cq));
                o2.x = __fadd_rn(__fmul_rn(v2.x, omc), __fmul_rn(s2v.x, cq));
                o2.y = __fadd_rn(__fmul_rn(v2.y, omc), __fmul_rn(s2v.y, cq));
                o2.z = __fadd_rn(__fmul_rn(v2.z, omc), __fmul_rn(s2v.z, cq));
                o2.w = __fadd_rn(__fmul_rn(v2.w, omc), __fmul_rn(s2v.w, cq));
                o3.x = __fadd_rn(__fmul_rn(v3.x, omc), __fmul_rn(s3v.x, cq));
                o3.y = __fadd_rn(__fmul_rn(v3.y, omc), __fmul_rn(s3v.y, cq));
                o3.z = __fadd_rn(__fmul_rn(v3.z, omc), __fmul_rn(s3v.z, cq));
                o3.w = __fadd_rn(__fmul_rn(v3.w, omc), __fmul_rn(s3v.w, cq));
                *(float4*)(dst + 0)  = o0;
                *(float4*)(dst + 4)  = o1;
                *(float4*)(dst + 8)  = o2;
                *(float4*)(dst + 12) = o3;
                qc0 = o0; qc1 = o1; qc2 = o2; qc3 = o3; qCode = NM + b;
            }
            __syncthreads();

            // phase 4/5
            if (condSb || !condQ) {
                unsigned lk2 = 0;
                for (int g = lane; g < G; g += 64) {
                    unsigned k = fkey(-gIdxS[g]);
                    if (k > lk2) lk2 = k;
                }
                lk2 = waveMaxU32(lk2);
                float mxneg = fkeyInv(lk2);
                bool lmatch = false;
                for (int g = lane; g < G; g += 64)
                    if (gIdxS[g] == mxneg) lmatch = true;
                if (__any(lmatch ? 1 : 0)) {
                    float nIdx  = condSb ? uIdx  : sF;
                    float nLast = condSb ? uLast : sF;
                    unsigned short nRow = (unsigned short)(condSb ? (2 * NM + b) : (3 * NM + b));
                    if (lane == 0) { cntSh = 0; mMinSh = 0x7fffffff; }
                    __syncthreads();
                    int lm = 0x7fffffff;
                    for (int g = lane; g < G; g += 64) {
                        if (gIdxS[g] == mxneg) {
                            int ms = gMinS[g];
                            if (ms < lm) lm = ms;
                        } else {
                            int pos = atomicAdd(&cntSh, 1);
                            stRow[pos] = gRowS[g]; stMin[pos] = gMinS[g];
                            stIdx[pos] = gIdxS[g]; stLast[pos] = gLastS[g];
                        }
                    }
                    if (lm != 0x7fffffff) atomicMin(&mMinSh, lm);
                    __syncthreads();
                    int cnt = cntSh;
                    for (int i = lane; i < cnt; i += 64) {
                        gRowS[i] = stRow[i];
                        gMinS[i] = stMin[i];
                        gIdxS[i] = stIdx[i];
                        gLastS[i] = stLast[i];
                    }
                    if (lane == 0) {
                        gRowS[cnt] = nRow; gIdxS[cnt] = nIdx;
                        gLastS[cnt] = nLast; gMinS[cnt] = (unsigned short)mMinSh;
                    }
                    G = cnt + 1;
                    __syncthreads();
                }
            }

            // phase 6
            unsigned long long lk3 = 0; int lp3 = 0;
            for (int g = lane; g < G; g += 64) {
                unsigned long long kk = packKey(gIdxS[g], (int)gMinS[g]);
                if (kk > lk3) { lk3 = kk; lp3 = g; }
            }
            #pragma unroll
            for (int off = 1; off < 64; off <<= 1) {
                unsigned long long ko = (unsigned long long)__shfl_xor((long long)lk3, off, 64);
                int po = __shfl_xor(lp3, off, 64);
                if (ko > lk3) { lk3 = ko; lp3 = po; }
            }
            if (lane == 0) {
                leadCode[b] = (int)gRowS[lp3];
                out[(size_t)NB * NF + b] = fkeyInv((unsigned)(lk3 >> 32));
            }

            // ---- transition to DPP register mode ----
            if (G <= 16) {
                __syncthreads();
                valid = (lane < G);
                rowR  = valid ? (int)gRowS[lane] : 0;
                minR  = valid ? (unsigned)gMinS[lane] : 0u;
                idxR  = valid ? gIdxS[lane] : 0.f;
                lastR = valid ? gLastS[lane] : 0.f;
                predR = (valid && rowR < NM) ? pOr[rowR] : 0ull;
                dppMode = true;
            }
        }
    }
}

// Deferred, fully-parallel leader-row copy (pool rows are append-only -> safe).
__global__ void __launch_bounds__(256) k_final(
        const int* __restrict__ leadCode, const float* __restrict__ memory,
        const float* __restrict__ vecq, const float* __restrict__ UMS,
        const float* __restrict__ states, float* __restrict__ out) {
    int b = blockIdx.x, t = threadIdx.x;
    const float* p = rowPtr(leadCode[b], memory, vecq, UMS, states);
    float4 v = ((const float4*)p)[t];
    ((float4*)(out + (size_t)b * NF))[t] = v;
}

extern "C" void kernel_launch(void* const* d_in, const int* in_sizes, int n_in,
                              void* d_out, int out_size, void* d_ws, size_t ws_size,
                              hipStream_t stream) {
    (void)out_size;
    const float* states  = (const float*)d_in[0];
    const float* mr      = (const float*)d_in[1];
    const float* memory  = (const float*)d_in[2];
    const float* indexIn = (const float*)d_in[3];
    for (int i = 0; i < n_in; ++i) {
        switch (in_sizes[i]) {
            case NB * NT * NF: states  = (const float*)d_in[i]; break;
            case NB * NS * NF: mr      = (const float*)d_in[i]; break;
            case NM * NF:      memory  = (const float*)d_in[i]; break;
            case NM:           indexIn = (const float*)d_in[i]; break;
            default: break;
        }
    }
    float* out = (float*)d_out;  // f32: 64*1024 targets + 64 importances

    char* ws = (char*)d_ws;
    float* UMS      = (float*)ws;                                      // 262144 B
    float* updIdxS  = (float*)(ws + 262144);                           // 256 B
    int*   condS    = (int*)(ws + 262400);                             // 256 B
    unsigned long long* predOrig = (unsigned long long*)(ws + 262656); // 16384 -> 279040
    float* memLast  = (float*)(ws + 279040);                           // 8192  -> 287232
    float* vecq     = (float*)(ws + 287232);                           // 262144 -> 549376
    int*   leadCode = (int*)(ws + 549376);                             // 256   -> 549632
    // 549632..582400 reserved
    float* pMin     = (float*)(ws + 582400);                           // 262144 -> 844544
    float* pMax     = (float*)(ws + 844544);                           // 262144 -> 1106688
    bool twoStage = (ws_size >= 1106688);

    if (twoStage) {
        k_pre<<<dim3(NB * 16 + NM), 256, 0, stream>>>(mr, memory, states, pMin, pMax,
                                                      predOrig, memLast, 1);
        k_routes2<<<dim3(NB), 1024, 0, stream>>>(pMin, pMax, mr, states, UMS, updIdxS, condS);
    } else {
        k_pre<<<dim3(NB * 16 + NM), 256, 0, stream>>>(mr, memory, states, nullptr, nullptr,
                                                      predOrig, memLast, 0);
        k_routes<<<dim3(NB), 1024, 0, stream>>>(mr, states, UMS, updIdxS, condS);
    }
    k_scan<<<1, 64, 0, stream>>>(states, memory, indexIn, UMS, updIdxS, condS,
                                 predOrig, memLast, vecq, leadCode, out);
    k_final<<<NB, 256, 0, stream>>>(leadCode, memory, vecq, UMS, states, out);
}

// Round 5
// 312.262 us; speedup vs baseline: 1.0193x; 1.0193x over previous
//
#include <hip/hip_runtime.h>
#include <stdint.h>

#define NB 64    // scan steps (B)
#define NT 128   // T
#define NF 1024  // F
#define NS 512   // S
#define NM 2048  // M
#define SQRT_S 22.627417f  // correctly-rounded f32 of sqrt(512)

// 0.5 - hard_sigmoid(x - s), numpy-identical per-op rounding.
__device__ __forceinline__ float comp_of(float x, float s) {
    float d = __fsub_rn(x, s);
    float t = __fadd_rn(__fmul_rn(0.2f, d), 0.5f);
    t = fminf(fmaxf(t, 0.0f), 1.0f);
    return __fsub_rn(0.5f, t);
}

// order-isomorphic f32 <-> u32 (NaN-free). Invertible: decode gives bit-exact float.
__device__ __forceinline__ unsigned fkey(float x) {
    unsigned u = __float_as_uint(x);
    return (u & 0x80000000u) ? ~u : (u | 0x80000000u);
}
__device__ __forceinline__ float fkeyInv(unsigned k) {
    return (k & 0x80000000u) ? __uint_as_float(k & 0x7fffffffu) : __uint_as_float(~k);
}
// larger key = larger value, ties -> smaller slot (np.argmax first-index semantics).
__device__ __forceinline__ unsigned long long packKey(float v, int m) {
    return ((unsigned long long)fkey(v) << 32) | (unsigned)(NM - m);
}

// Row code -> pointer. code<NM: original memory row; <2NM: q-blend row (vecq[b]);
// <3NM: UMS row b; else: states row b (last timestep).
__device__ __forceinline__ const float* rowPtr(int code, const float* memory,
                                               const float* vecq, const float* UMS,
                                               const float* states) {
    if (code < NM)     return memory + (size_t)code * NF;
    if (code < 2 * NM) return vecq + (size_t)(code - NM) * NF;
    if (code < 3 * NM) return UMS + (size_t)(code - 2 * NM) * NF;
    return states + ((size_t)(code - 3 * NM) * NT + NT - 1) * NF;
}

// ---- cheap cross-lane helpers (VALU/SALU pipes, no ds ops) ----
__device__ __forceinline__ unsigned rflu(unsigned v) {
    return (unsigned)__builtin_amdgcn_readfirstlane((int)v);
}
__device__ __forceinline__ int rdl(int v, int l) { return __builtin_amdgcn_readlane(v, l); }
__device__ __forceinline__ float rdlf(float v, int l) {
    return __uint_as_float((unsigned)__builtin_amdgcn_readlane((int)__float_as_uint(v), l));
}
// 16-lane (row) max via DPP: quad xor1, quad xor2, row_half_mirror, row_mirror.
// After this every lane of each row holds the row max.
__device__ __forceinline__ unsigned row16MaxU32(unsigned x) {
    unsigned t;
    t = (unsigned)__builtin_amdgcn_update_dpp(0, (int)x, 0xB1, 0xF, 0xF, true);   // quad_perm(1,0,3,2)
    x = (t > x) ? t : x;
    t = (unsigned)__builtin_amdgcn_update_dpp(0, (int)x, 0x4E, 0xF, 0xF, true);   // quad_perm(2,3,0,1)
    x = (t > x) ? t : x;
    t = (unsigned)__builtin_amdgcn_update_dpp(0, (int)x, 0x141, 0xF, 0xF, true);  // row_half_mirror
    x = (t > x) ? t : x;
    t = (unsigned)__builtin_amdgcn_update_dpp(0, (int)x, 0x140, 0xF, 0xF, true);  // row_mirror
    x = (t > x) ? t : x;
    return x;
}

// ---- 64-wide butterflies (LDS-mode only; a few early steps) ----
__device__ __forceinline__ unsigned waveMaxU32(unsigned k) {
    #pragma unroll
    for (int off = 1; off < 64; off <<= 1) {
        unsigned o = __shfl_xor(k, off, 64);
        if (o > k) k = o;
    }
    return k;
}

// ---- fused: routes stage-1 (first 1024 blocks) + predorig/memLast (next 2048) ----
__global__ void __launch_bounds__(256) k_pre(
        const float* __restrict__ mr, const float* __restrict__ memory,
        const float* __restrict__ states,
        float* __restrict__ pMin, float* __restrict__ pMax,
        unsigned long long* __restrict__ predOrig, float* __restrict__ memLast,
        int doRoutes)
{
    int bid = blockIdx.x;
    if (bid < NB * 16) {
        if (!doRoutes) return;
        int b = bid >> 4, fb = (bid >> 2) & 3, seg = bid & 3;
        int f = fb * 256 + threadIdx.x;
        const float* base = mr + (size_t)b * NS * NF + (size_t)seg * (NS / 4) * NF + f;
        float mn0 = base[0],      mx0 = mn0;
        float mn1 = base[NF],     mx1 = mn1;
        float mn2 = base[2 * NF], mx2 = mn2;
        float mn3 = base[3 * NF], mx3 = mn3;
        #pragma unroll 4
        for (int s = 4; s < NS / 4; s += 4) {
            float v0 = base[(size_t)s * NF];
            float v1 = base[(size_t)(s + 1) * NF];
            float v2 = base[(size_t)(s + 2) * NF];
            float v3 = base[(size_t)(s + 3) * NF];
            mn0 = fminf(mn0, v0); mx0 = fmaxf(mx0, v0);
            mn1 = fminf(mn1, v1); mx1 = fmaxf(mx1, v1);
            mn2 = fminf(mn2, v2); mx2 = fmaxf(mx2, v2);
            mn3 = fminf(mn3, v3); mx3 = fmaxf(mx3, v3);
        }
        size_t o = ((size_t)seg * NB + b) * NF + f;
        pMin[o] = fminf(fminf(mn0, mn1), fminf(mn2, mn3));
        pMax[o] = fmaxf(fmaxf(mx0, mx1), fmaxf(mx2, mx3));
        return;
    }
    // predorig part
    int m = bid - NB * 16, t = threadIdx.x;
    const float4* rowp = (const float4*)(memory + (size_t)m * NF);
    float4 v = rowp[t];
    unsigned long long mask = 0ull;
    for (int b = 0; b < NB; ++b) {
        const float4* spp = (const float4*)(states + ((size_t)b * NT + NT - 1) * NF);
        float4 s = spp[t];
        bool p = (comp_of(v.x, s.x) >= 0.45f) | (comp_of(v.y, s.y) >= 0.45f)
               | (comp_of(v.z, s.z) >= 0.45f) | (comp_of(v.w, s.w) >= 0.45f);
        if (p) mask |= (1ull << b);
    }
    __shared__ unsigned long long sm[256];
    sm[t] = mask;
    __syncthreads();
    for (int off = 128; off > 0; off >>= 1) {
        if (t < off) sm[t] |= sm[t + off];
        __syncthreads();
    }
    if (t == 0)   predOrig[m] = sm[0];
    if (t == 255) memLast[m] = v.w;
}

// Shared epilogue: UMS row, condS (written once per b), updIdxS.
__device__ __forceinline__ void routes_epilogue(int b, int f, float mn, float mx,
        const float* mr, const float* states, float* UMS, float* updIdxS, int* condS,
        int* anyf) {
    float sv = states[((size_t)b * NT + NT - 1) * NF + f];
    float compHi = comp_of(mn, sv);
    float compLo = comp_of(mx, sv);
    float maxabs = fmaxf(compHi, -compLo);
    float cs   = __fmul_rn(SQRT_S, maxabs);
    float omcs = __fsub_rn(1.0f, cs);
    UMS[(size_t)b * NF + f] = __fadd_rn(__fmul_rn(mx, cs), __fmul_rn(sv, omcs));
    if (f == 0) *anyf = 0;
    __syncthreads();
    if (compHi >= 0.45f) atomicOr(anyf, 1);
    __syncthreads();
    if (f == 0) condS[b] = (*anyf) ? 1 : 0;
    if (f == NF - 1) {
        float mr0l = mr[(size_t)b * NS * NF + NF - 1];  // mr[b, 0, F-1]
        updIdxS[b] = __fadd_rn(__fmul_rn(mr0l, cs), __fmul_rn(sv, omcs));
    }
}

// ---- stage 2: combine segments + epilogue. One 1024-thread block per b. ----
__global__ void __launch_bounds__(1024) k_routes2(
        const float* __restrict__ pMin, const float* __restrict__ pMax,
        const float* __restrict__ mr, const float* __restrict__ states,
        float* __restrict__ UMS, float* __restrict__ updIdxS,
        int* __restrict__ condS) {
    __shared__ int anyf;
    int b = blockIdx.x;
    int f = threadIdx.x;
    float mn = INFINITY, mx = -INFINITY;
    #pragma unroll
    for (int seg = 0; seg < 4; ++seg) {
        size_t o = ((size_t)seg * NB + b) * NF + f;
        mn = fminf(mn, pMin[o]);
        mx = fmaxf(mx, pMax[o]);
    }
    routes_epilogue(b, f, mn, mx, mr, states, UMS, updIdxS, condS, &anyf);
}

// ---- fallback single-stage (if ws too small). One 1024-thread block per b. ----
__global__ void __launch_bounds__(1024) k_routes(
        const float* __restrict__ mr, const float* __restrict__ states,
        float* __restrict__ UMS, float* __restrict__ updIdxS,
        int* __restrict__ condS) {
    __shared__ int anyf;
    int b = blockIdx.x;
    int f = threadIdx.x;
    const float* base = mr + (size_t)b * NS * NF + f;
    float mn0 = base[0],      mx0 = mn0;
    float mn1 = base[NF],     mx1 = mn1;
    float mn2 = base[2 * NF], mx2 = mn2;
    float mn3 = base[3 * NF], mx3 = mn3;
    #pragma unroll 4
    for (int s = 4; s < NS; s += 4) {
        float v0 = base[(size_t)s * NF];
        float v1 = base[(size_t)(s + 1) * NF];
        float v2 = base[(size_t)(s + 2) * NF];
        float v3 = base[(size_t)(s + 3) * NF];
        mn0 = fminf(mn0, v0); mx0 = fmaxf(mx0, v0);
        mn1 = fminf(mn1, v1); mx1 = fmaxf(mx1, v1);
        mn2 = fminf(mn2, v2); mx2 = fmaxf(mx2, v2);
        mn3 = fminf(mn3, v3); mx3 = fmaxf(mx3, v3);
    }
    float mn = fminf(fminf(mn0, mn1), fminf(mn2, mn3));
    float mx = fmaxf(fmaxf(mx0, mx1), fmaxf(mx2, mx3));
    routes_epilogue(b, f, mn, mx, mr, states, UMS, updIdxS, condS, &anyf);
}

// Sequential scan, SINGLE WAVE, group-collapsed carry.
// Steady state (R2's 87us structure, straight-line): groups in lanes 0..15,
// DPP reductions + readfirstlane broadcasts. ONE change vs the 87us baseline:
// a winner-source register cache (wCache) -- the phase-1 winner is kept and its
// `last` never changes, so the same source row wins for runs of steps; caching
// the loaded row by its immutable code removes the per-step L2-hit vmcnt stall.
__global__ void __launch_bounds__(64) k_scan(
    const float* __restrict__ states, const float* __restrict__ memory,
    const float* __restrict__ indexIn, const float* __restrict__ UMS,
    const float* __restrict__ updIdxS, const int* __restrict__ condS,
    const unsigned long long* __restrict__ predOrig,
    const float* __restrict__ memLast, float* __restrict__ vecq,
    int* __restrict__ leadCode, float* __restrict__ out)
{
    __shared__ float gLastS[NM];
    __shared__ float gIdxS[NM];
    __shared__ unsigned short gRowS[NM];
    __shared__ unsigned short gMinS[NM];
    __shared__ unsigned long long pOr[NM];
    __shared__ float stLast[NM];
    __shared__ float stIdx[NM];
    __shared__ unsigned short stRow[NM];
    __shared__ unsigned short stMin[NM];
    __shared__ int cntSh;
    __shared__ int mMinSh;

    const int lane = threadIdx.x;

    for (int m = lane; m < NM; m += 64) {
        gRowS[m] = (unsigned short)m;
        gMinS[m] = (unsigned short)m;
        gIdxS[m] = indexIn[m];
        gLastS[m] = memLast[m];
        pOr[m] = predOrig[m];
    }
    // per-step scalars: lane b holds step b's values; broadcast via readlane
    float sF_r = states[((size_t)lane * NT + NT - 1) * NF + NF - 1];
    int   cS_r = condS[lane];
    float uI_r = updIdxS[lane];
    float uL_r = UMS[(size_t)lane * NF + NF - 1];
    __syncthreads();

    int G = NM;
    bool dppMode = false;
    int rowR = 0; unsigned minR = 0;
    float idxR = 0.f, lastR = 0.f;
    unsigned long long predR = 0ull;
    bool valid = false;
    int qCode = -1;                       // last-created q-row cached in registers
    float4 qc0, qc1, qc2, qc3;
    int wCode = -2;                       // last-loaded winner-source row cache
    float4 wc0, wc1, wc2, wc3;

    // software prefetch of states rows: load row for step b at step b-1
    const float* sp0 = states + (size_t)(NT - 1) * NF + 16 * lane;
    float4 sN0 = *(const float4*)(sp0 + 0);
    float4 sN1 = *(const float4*)(sp0 + 4);
    float4 sN2 = *(const float4*)(sp0 + 8);
    float4 sN3 = *(const float4*)(sp0 + 12);

    #pragma unroll 1
    for (int b = 0; b < NB; ++b) {
        float4 s0v = sN0, s1v = sN1, s2v = sN2, s3v = sN3;
        if (b + 1 < NB) {
            const float* np = states + ((size_t)(b + 1) * NT + NT - 1) * NF + 16 * lane;
            sN0 = *(const float4*)(np + 0);
            sN1 = *(const float4*)(np + 4);
            sN2 = *(const float4*)(np + 8);
            sN3 = *(const float4*)(np + 12);
        }
        float sF    = rdlf(sF_r, b);   // == s[F-1] == r
        bool condSb = (rdl(cS_r, b) != 0);
        float uIdx  = rdlf(uI_r, b);
        float uLast = rdlf(uL_r, b);

        if (dppMode) {
            // ================= DPP mode (valid lanes subset of 0..15) =================
            // phase 1: argmax comp(last) with first-slot ties; cond_q from pred bits
            float c1 = comp_of(lastR, sF);
            unsigned kf = valid ? fkey(c1) : 0u;
            unsigned bkf = rflu(row16MaxU32(kf));
            bool isMax = valid && (kf == bkf);
            unsigned tb = isMax ? (unsigned)(NM - (int)minR) : 0u;
            unsigned btb = rflu(row16MaxU32(tb));
            int winLane = __ffsll(__ballot(isMax && tb == btb)) - 1;
            bool condQ = (__any((valid && rowR < NM && ((predR >> b) & 1ull)) ? 1 : 0) != 0);
            float cq = fkeyInv(bkf);                  // bit-exact winner comp
            int   srow   = rdl(rowR, winLane);
            float idxmi  = rdlf(idxR, winLane);
            float lastmi = rdlf(lastR, winLane);

            // phase 2: pool-row full check only if orig bits missed (rare)
            if (!condQ) {
                unsigned long long pm = __ballot((valid && rowR >= NM) ? 1 : 0);
                while (pm) {
                    int gl = __ffsll(pm) - 1; pm &= pm - 1;
                    int prow = rdl(rowR, gl);
                    float4 v0, v1, v2, v3;
                    if (prow == qCode) { v0 = qc0; v1 = qc1; v2 = qc2; v3 = qc3; }
                    else {
                        const float* p = rowPtr(prow, memory, vecq, UMS, states) + 16 * lane;
                        v0 = *(const float4*)(p + 0);
                        v1 = *(const float4*)(p + 4);
                        v2 = *(const float4*)(p + 8);
                        v3 = *(const float4*)(p + 12);
                    }
                    int pr = (comp_of(v0.x, s0v.x) >= 0.45f) | (comp_of(v0.y, s0v.y) >= 0.45f) |
                             (comp_of(v0.z, s0v.z) >= 0.45f) | (comp_of(v0.w, s0v.w) >= 0.45f) |
                             (comp_of(v1.x, s1v.x) >= 0.45f) | (comp_of(v1.y, s1v.y) >= 0.45f) |
                             (comp_of(v1.z, s1v.z) >= 0.45f) | (comp_of(v1.w, s1v.w) >= 0.45f) |
                             (comp_of(v2.x, s2v.x) >= 0.45f) | (comp_of(v2.y, s2v.y) >= 0.45f) |
                             (comp_of(v2.z, s2v.z) >= 0.45f) | (comp_of(v2.w, s2v.w) >= 0.45f) |
                             (comp_of(v3.x, s3v.x) >= 0.45f) | (comp_of(v3.y, s3v.y) >= 0.45f) |
                             (comp_of(v3.z, s3v.z) >= 0.45f) | (comp_of(v3.w, s3v.w) >= 0.45f);
                    if (__any(pr)) { condQ = true; break; }
                }
            }

            // phase 3: q-update — merge all non-max groups into one new group
            if (condQ) {
                float omc = __fsub_rn(1.0f, cq);
                float updIdxQ = __fadd_rn(__fmul_rn(idxmi, omc), __fmul_rn(sF, cq));
                float newLast = __fadd_rn(__fmul_rn(lastmi, omc), __fmul_rn(sF, cq));
                float4 v0, v1, v2, v3;
                if (srow == qCode)      { v0 = qc0; v1 = qc1; v2 = qc2; v3 = qc3; }
                else if (srow == wCode) { v0 = wc0; v1 = wc1; v2 = wc2; v3 = wc3; }
                else {
                    const float* srcp = rowPtr(srow, memory, vecq, UMS, states) + 16 * lane;
                    v0 = *(const float4*)(srcp + 0);
                    v1 = *(const float4*)(srcp + 4);
                    v2 = *(const float4*)(srcp + 8);
                    v3 = *(const float4*)(srcp + 12);
                    wc0 = v0; wc1 = v1; wc2 = v2; wc3 = v3; wCode = srow;
                }
                bool kept = valid && (c1 == cq);       // float == like reference mask
                unsigned long long keepM  = __ballot(kept ? 1 : 0);
                unsigned long long mergeM = __ballot((valid && !kept) ? 1 : 0);
                if (mergeM) {
                    unsigned mt = (valid && !kept) ? (unsigned)(NM - (int)minR) : 0u;
                    unsigned newMin = (unsigned)(NM - (int)rflu(row16MaxU32(mt)));
                    int freeLane = __ffsll(~keepM) - 1;      // lowest non-kept lane (<16)
                    if (lane == freeLane) {
                        rowR = NM + b; idxR = updIdxQ; lastR = newLast;
                        minR = newMin; predR = 0ull;
                    }
                    valid = kept || (lane == freeLane);
                }
                // blend + store + cache (off the control critical path)
                float* dst = vecq + (size_t)b * NF + 16 * lane;
                float4 o0, o1, o2, o3;
                o0.x = __fadd_rn(__fmul_rn(v0.x, omc), __fmul_rn(s0v.x, cq));
                o0.y = __fadd_rn(__fmul_rn(v0.y, omc), __fmul_rn(s0v.y, cq));
                o0.z = __fadd_rn(__fmul_rn(v0.z, omc), __fmul_rn(s0v.z, cq));
                o0.w = __fadd_rn(__fmul_rn(v0.w, omc), __fmul_rn(s0v.w, cq));
                o1.x = __fadd_rn(__fmul_rn(v1.x, omc), __fmul_rn(s1v.x, cq));
                o1.y = __fadd_rn(__fmul_rn(v1.y, omc), __fmul_rn(s1v.y, cq));
                o1.z = __fadd_rn(__fmul_rn(v1.z, omc), __fmul_rn(s1v.z, cq));
                o1.w = __fadd_rn(__fmul_rn(v1.w, omc), __fmul_rn(s1v.w, cq));
                o2.x = __fadd_rn(__fmul_rn(v2.x, omc), __fmul_rn(s2v.x, cq));
                o2.y = __fadd_rn(__fmul_rn(v2.y, omc), __fmul_rn(s2v.y, cq));
                o2.z = __fadd_rn(__fmul_rn(v2.z, omc), __fmul_rn(s2v.z, cq));
                o2.w = __fadd_rn(__fmul_rn(v2.w, omc), __fmul_rn(s2v.w, cq));
                o3.x = __fadd_rn(__fmul_rn(v3.x, omc), __fmul_rn(s3v.x, cq));
                o3.y = __fadd_rn(__fmul_rn(v3.y, omc), __fmul_rn(s3v.y, cq));
                o3.z = __fadd_rn(__fmul_rn(v3.z, omc), __fmul_rn(s3v.z, cq));
                o3.w = __fadd_rn(__fmul_rn(v3.w, omc), __fmul_rn(s3v.w, cq));
                *(float4*)(dst + 0)  = o0;
                *(float4*)(dst + 4)  = o1;
                *(float4*)(dst + 8)  = o2;
                *(float4*)(dst + 12) = o3;
                qc0 = o0; qc1 = o1; qc2 = o2; qc3 = o3; qCode = NM + b;
            }

            // phase 4/5: s-update or empty-update (mutually exclusive)
            if (condSb || !condQ) {
                unsigned kf2 = valid ? fkey(-idxR) : 0u;
                unsigned bkf2 = rflu(row16MaxU32(kf2));
                float mxneg = fkeyInv(bkf2);             // bit-exact max(-idx)
                bool match = valid && (idxR == mxneg);
                unsigned long long matchM = __ballot(match ? 1 : 0);
                if (matchM) {
                    unsigned mt = match ? (unsigned)(NM - (int)minR) : 0u;
                    unsigned newMin = (unsigned)(NM - (int)rflu(row16MaxU32(mt)));
                    unsigned long long nv = __ballot((valid && !match) ? 1 : 0);
                    int freeLane = __ffsll(~nv) - 1;
                    if (lane == freeLane) {
                        rowR = condSb ? (2 * NM + b) : (3 * NM + b);
                        idxR = condSb ? uIdx : sF;
                        lastR = condSb ? uLast : sF;
                        minR = newMin; predR = 0ull;
                    }
                    valid = (valid && !match) || (lane == freeLane);
                }
            }

            // phase 6: leader = first-argmax(idx); record row code + importance
            unsigned kf3 = valid ? fkey(idxR) : 0u;
            unsigned bkf3 = rflu(row16MaxU32(kf3));
            bool is3 = valid && (kf3 == bkf3);
            unsigned tb3 = is3 ? (unsigned)(NM - (int)minR) : 0u;
            unsigned btb3 = rflu(row16MaxU32(tb3));
            int lg = __ffsll(__ballot(is3 && tb3 == btb3)) - 1;
            int lrow = rdl(rowR, lg);
            if (lane == 0) {
                leadCode[b] = lrow;
                out[(size_t)NB * NF + b] = fkeyInv(bkf3);
            }
        } else {
            // ================= LDS mode (G > 16; early steps) =================
            // phase 1
            unsigned long long lk = 0; int lp = 0; bool lo = false;
            for (int g = lane; g < G; g += 64) {
                float c = comp_of(gLastS[g], sF);
                unsigned long long kk = packKey(c, (int)gMinS[g]);
                if (kk > lk) { lk = kk; lp = g; }
                int row = gRowS[g];
                if (row < NM && ((pOr[row] >> b) & 1ull)) lo = true;
            }
            #pragma unroll
            for (int off = 1; off < 64; off <<= 1) {
                unsigned long long ko = (unsigned long long)__shfl_xor((long long)lk, off, 64);
                int po = __shfl_xor(lp, off, 64);
                if (ko > lk) { lk = ko; lp = po; }
            }
            unsigned long long bk = lk; int miG = lp;
            bool condQ = (__any(lo ? 1 : 0) != 0);
            if (!condQ) {
                for (int g = 0; g < G && !condQ; ++g) {
                    int row = gRowS[g];
                    if (row >= NM) {
                        float4 v0, v1, v2, v3;
                        if (row == qCode) { v0 = qc0; v1 = qc1; v2 = qc2; v3 = qc3; }
                        else {
                            const float* p = rowPtr(row, memory, vecq, UMS, states) + 16 * lane;
                            v0 = *(const float4*)(p + 0);
                            v1 = *(const float4*)(p + 4);
                            v2 = *(const float4*)(p + 8);
                            v3 = *(const float4*)(p + 12);
                        }
                        int pr = (comp_of(v0.x, s0v.x) >= 0.45f) | (comp_of(v0.y, s0v.y) >= 0.45f) |
                                 (comp_of(v0.z, s0v.z) >= 0.45f) | (comp_of(v0.w, s0v.w) >= 0.45f) |
                                 (comp_of(v1.x, s1v.x) >= 0.45f) | (comp_of(v1.y, s1v.y) >= 0.45f) |
                                 (comp_of(v1.z, s1v.z) >= 0.45f) | (comp_of(v1.w, s1v.w) >= 0.45f) |
                                 (comp_of(v2.x, s2v.x) >= 0.45f) | (comp_of(v2.y, s2v.y) >= 0.45f) |
                                 (comp_of(v2.z, s2v.z) >= 0.45f) | (comp_of(v2.w, s2v.w) >= 0.45f) |
                                 (comp_of(v3.x, s3v.x) >= 0.45f) | (comp_of(v3.y, s3v.y) >= 0.45f) |
                                 (comp_of(v3.z, s3v.z) >= 0.45f) | (comp_of(v3.w, s3v.w) >= 0.45f);
                        if (__any(pr)) condQ = true;
                    }
                }
            }

            // phase 3: q-update via LDS-staged compaction
            if (condQ) {
                float cq = fkeyInv((unsigned)(bk >> 32));
                float omc = __fsub_rn(1.0f, cq);
                int srow = gRowS[miG];
                float idxmi = gIdxS[miG];
                float lastmi = gLastS[miG];
                float updIdxQ = __fadd_rn(__fmul_rn(idxmi, omc), __fmul_rn(sF, cq));
                float newLast = __fadd_rn(__fmul_rn(lastmi, omc), __fmul_rn(sF, cq));
                float4 v0, v1, v2, v3;
                if (srow == qCode) { v0 = qc0; v1 = qc1; v2 = qc2; v3 = qc3; }
                else {
                    const float* srcp = rowPtr(srow, memory, vecq, UMS, states) + 16 * lane;
                    v0 = *(const float4*)(srcp + 0);
                    v1 = *(const float4*)(srcp + 4);
                    v2 = *(const float4*)(srcp + 8);
                    v3 = *(const float4*)(srcp + 12);
                }

                bool lmerged = false;
                for (int g = lane; g < G; g += 64)
                    if (comp_of(gLastS[g], sF) != cq) lmerged = true;
                if (__any(lmerged ? 1 : 0)) {
                    if (lane == 0) { cntSh = 0; mMinSh = 0x7fffffff; }
                    __syncthreads();
                    int lm = 0x7fffffff;
                    for (int g = lane; g < G; g += 64) {
                        float c = comp_of(gLastS[g], sF);
                        if (c == cq) {
                            int pos = atomicAdd(&cntSh, 1);
                            stRow[pos] = gRowS[g]; stMin[pos] = gMinS[g];
                            stIdx[pos] = gIdxS[g]; stLast[pos] = gLastS[g];
                        } else {
                            int ms = gMinS[g];
                            if (ms < lm) lm = ms;
                        }
                    }
                    if (lm != 0x7fffffff) atomicMin(&mMinSh, lm);
                    __syncthreads();
                    int cnt = cntSh;
                    for (int i = lane; i < cnt; i += 64) {
                        gRowS[i] = stRow[i];
                        gMinS[i] = stMin[i];
                        gIdxS[i] = stIdx[i];
                        gLastS[i] = stLast[i];
                    }
                    if (lane == 0) {
                        gRowS[cnt] = (unsigned short)(NM + b);
                        gIdxS[cnt] = updIdxQ;
                        gLastS[cnt] = newLast;
                        gMinS[cnt] = (unsigned short)mMinSh;
                    }
                    G = cnt + 1;
                    __syncthreads();
                }

                float* dst = vecq + (size_t)b * NF + 16 * lane;
                float4 o0, o1, o2, o3;
                o0.x = __fadd_rn(__fmul_rn(v0.x, omc), __fmul_rn(s0v.x, cq));
                o0.y = __fadd_rn(__fmul_rn(v0.y, omc), __fmul_rn(s0v.y, cq));
                o0.z = __fadd_rn(__fmul_rn(v0.z, omc), __fmul_rn(s0v.z, cq));
                o0.w = __fadd_rn(__fmul_rn(v0.w, omc), __fmul_rn(s0v.w, cq));
                o1.x = __fadd_rn(__fmul_rn(v1.x, omc), __fmul_rn(s1v.x, cq));
                o1.y = __fadd_rn(__fmul_rn(v1.y, omc), __fmul_rn(s1v.y, cq));
                o1.z = __fadd_rn(__fmul_rn(v1.z, omc), __fmul_rn(s1v.z, cq));
                o1.w = __fadd_rn(__fmul_rn(v1.w, omc), __fmul_rn(s1v.w, cq));
                o2.x = __fadd_rn(__fmul_rn(v2.x, omc), __fmul_rn(s2v.x, cq));
                o2.y = __fadd_rn(__fmul_rn(v2.y, omc), __fmul_rn(s2v.y, cq));
                o2.z = __fadd_rn(__fmul_rn(v2.z, omc), __fmul_rn(s2v.z, cq));
                o2.w = __fadd_rn(__fmul_rn(v2.w, omc), __fmul_rn(s2v.w, cq));
                o3.x = __fadd_rn(__fmul_rn(v3.x, omc), __fmul_rn(s3v.x, cq));
                o3.y = __fadd_rn(__fmul_rn(v3.y, omc), __fmul_rn(s3v.y, cq));
                o3.z = __fadd_rn(__fmul_rn(v3.z, omc), __fmul_rn(s3v.z, cq));
                o3.w = __fadd_rn(__fmul_rn(v3.w, omc), __fmul_rn(s3v.w, cq));
                *(float4*)(dst + 0)  = o0;
                *(float4*)(dst + 4)  = o1;
                *(float4*)(dst + 8)  = o2;
                *(float4*)(dst + 12) = o3;
                qc0 = o0; qc1 = o1; qc2 = o2; qc3 = o3; qCode = NM + b;
            }
            __syncthreads();

            // phase 4/5
            if (condSb || !condQ) {
                unsigned lk2 = 0;
                for (int g = lane; g < G; g += 64) {
                    unsigned k = fkey(-gIdxS[g]);
                    if (k > lk2) lk2 = k;
                }
                lk2 = waveMaxU32(lk2);
                float mxneg = fkeyInv(lk2);
                bool lmatch = false;
                for (int g = lane; g < G; g += 64)
                    if (gIdxS[g] == mxneg) lmatch = true;
                if (__any(lmatch ? 1 : 0)) {
                    float nIdx  = condSb ? uIdx  : sF;
                    float nLast = condSb ? uLast : sF;
                    unsigned short nRow = (unsigned short)(condSb ? (2 * NM + b) : (3 * NM + b));
                    if (lane == 0) { cntSh = 0; mMinSh = 0x7fffffff; }
                    __syncthreads();
                    int lm = 0x7fffffff;
                    for (int g = lane; g < G; g += 64) {
                        if (gIdxS[g] == mxneg) {
                            int ms = gMinS[g];
                            if (ms < lm) lm = ms;
                        } else {
                            int pos = atomicAdd(&cntSh, 1);
                            stRow[pos] = gRowS[g]; stMin[pos] = gMinS[g];
                            stIdx[pos] = gIdxS[g]; stLast[pos] = gLastS[g];
                        }
                    }
                    if (lm != 0x7fffffff) atomicMin(&mMinSh, lm);
                    __syncthreads();
                    int cnt = cntSh;
                    for (int i = lane; i < cnt; i += 64) {
                        gRowS[i] = stRow[i];
                        gMinS[i] = stMin[i];
                        gIdxS[i] = stIdx[i];
                        gLastS[i] = stLast[i];
                    }
                    if (lane == 0) {
                        gRowS[cnt] = nRow; gIdxS[cnt] = nIdx;
                        gLastS[cnt] = nLast; gMinS[cnt] = (unsigned short)mMinSh;
                    }
                    G = cnt + 1;
                    __syncthreads();
                }
            }

            // phase 6
            unsigned long long lk3 = 0; int lp3 = 0;
            for (int g = lane; g < G; g += 64) {
                unsigned long long kk = packKey(gIdxS[g], (int)gMinS[g]);
                if (kk > lk3) { lk3 = kk; lp3 = g; }
            }
            #pragma unroll
            for (int off = 1; off < 64; off <<= 1) {
                unsigned long long ko = (unsigned long long)__shfl_xor((long long)lk3, off, 64);
                int po = __shfl_xor(lp3, off, 64);
                if (ko > lk3) { lk3 = ko; lp3 = po; }
            }
            if (lane == 0) {
                leadCode[b] = (int)gRowS[lp3];
                out[(size_t)NB * NF + b] = fkeyInv((unsigned)(lk3 >> 32));
            }

            // ---- transition to DPP register mode ----
            if (G <= 16) {
                __syncthreads();
                valid = (lane < G);
                rowR  = valid ? (int)gRowS[lane] : 0;
                minR  = valid ? (unsigned)gMinS[lane] : 0u;
                idxR  = valid ? gIdxS[lane] : 0.f;
                lastR = valid ? gLastS[lane] : 0.f;
                predR = (valid && rowR < NM) ? pOr[rowR] : 0ull;
                dppMode = true;
            }
        }
    }
}

// Deferred, fully-parallel leader-row copy (pool rows are append-only -> safe).
__global__ void __launch_bounds__(256) k_final(
        const int* __restrict__ leadCode, const float* __restrict__ memory,
        const float* __restrict__ vecq, const float* __restrict__ UMS,
        const float* __restrict__ states, float* __restrict__ out) {
    int b = blockIdx.x, t = threadIdx.x;
    const float* p = rowPtr(leadCode[b], memory, vecq, UMS, states);
    float4 v = ((const float4*)p)[t];
    ((float4*)(out + (size_t)b * NF))[t] = v;
}

extern "C" void kernel_launch(void* const* d_in, const int* in_sizes, int n_in,
                              void* d_out, int out_size, void* d_ws, size_t ws_size,
                              hipStream_t stream) {
    (void)out_size;
    const float* states  = (const float*)d_in[0];
    const float* mr      = (const float*)d_in[1];
    const float* memory  = (const float*)d_in[2];
    const float* indexIn = (const float*)d_in[3];
    for (int i = 0; i < n_in; ++i) {
        switch (in_sizes[i]) {
            case NB * NT * NF: states  = (const float*)d_in[i]; break;
            case NB * NS * NF: mr      = (const float*)d_in[i]; break;
            case NM * NF:      memory  = (const float*)d_in[i]; break;
            case NM:           indexIn = (const float*)d_in[i]; break;
            default: break;
        }
    }
    float* out = (float*)d_out;  // f32: 64*1024 targets + 64 importances

    char* ws = (char*)d_ws;
    float* UMS      = (float*)ws;                                      // 262144 B
    float* updIdxS  = (float*)(ws + 262144);                           // 256 B
    int*   condS    = (int*)(ws + 262400);                             // 256 B
    unsigned long long* predOrig = (unsigned long long*)(ws + 262656); // 16384 -> 279040
    float* memLast  = (float*)(ws + 279040);                           // 8192  -> 287232
    float* vecq     = (float*)(ws + 287232);                           // 262144 -> 549376
    int*   leadCode = (int*)(ws + 549376);                             // 256   -> 549632
    // 549632..582400 reserved
    float* pMin     = (float*)(ws + 582400);                           // 262144 -> 844544
    float* pMax     = (float*)(ws + 844544);                           // 262144 -> 1106688
    bool twoStage = (ws_size >= 1106688);

    if (twoStage) {
        k_pre<<<dim3(NB * 16 + NM), 256, 0, stream>>>(mr, memory, states, pMin, pMax,
                                                      predOrig, memLast, 1);
        k_routes2<<<dim3(NB), 1024, 0, stream>>>(pMin, pMax, mr, states, UMS, updIdxS, condS);
    } else {
        k_pre<<<dim3(NB * 16 + NM), 256, 0, stream>>>(mr, memory, states, nullptr, nullptr,
                                                      predOrig, memLast, 0);
        k_routes<<<dim3(NB), 1024, 0, stream>>>(mr, states, UMS, updIdxS, condS);
    }
    k_scan<<<1, 64, 0, stream>>>(states, memory, indexIn, UMS, updIdxS, condS,
                                 predOrig, memLast, vecq, leadCode, out);
    k_final<<<NB, 256, 0, stream>>>(leadCode, memory, vecq, UMS, states, out);
}